// Round 2
// baseline (907.457 us; speedup 1.0000x reference)
//
#include <hip/hip_runtime.h>

// ---------------------------------------------------------------------------
// GNN: 3x GraphConv (norm='both') + avg-pool + MLP(128->512->256->1), fp32.
// R15: R14 fusion (gather + MFMA GEMM in one kernel) with the in-place
// hazard fixed: layers ping-pong hsA <-> hsB (layer0 feats->hsA, layer1
// hsA->hsB, layer2 hsB->hsA). R14 read and wrote the same hs buffer in one
// dispatch -> cross-block RAW race (absmax 9.3e-3). Footprint identical to
// R13 (hs + aggp = 2 x 51.2MB); CSR temps alias hsB (dead until layer 1).
// Gather loop remains a verbatim port of csr_agg (bit-identical sums).
// ---------------------------------------------------------------------------

static inline int ceil_div(int a, int b){ return (a + b - 1) / b; }

#define B1 256          // scatter blocks == segments per bucket
#define NBMAX 1024      // max buckets (N <= 131072; src ids fit in 17 bits)
#define CHUNK_MAX 7168  // max edges per scatter block (E <= B1*CHUNK_MAX)
#define BUCKET_MAX 4096 // max edges per bucket (mean ~2048)
#define WPREP_BLOCKS 192

typedef __bf16 bf16x8 __attribute__((ext_vector_type(8)));
typedef float  f32x4  __attribute__((ext_vector_type(4)));

static __device__ inline __bf16 bits_to_bf16(unsigned short u){
  union { unsigned short u; __bf16 b; } x; x.u = u; return x.b;
}
static __device__ inline unsigned short bf16_bits(__bf16 b){
  union { __bf16 b; unsigned short u; } x; x.b = b; return x.u;
}
static __device__ inline unsigned pack_split(float s){
  __bf16 h = (__bf16)s;
  __bf16 l = (__bf16)(s - (float)h);
  return ((unsigned)bf16_bits(h) << 16) | (unsigned)bf16_bits(l);
}

// One-pass bucketed counting sort, block-local staging, coalesced flush.
// Also hosts wprep on blocks >= B1 (W fp32 -> split-bf16 [n][k]).
__global__ __launch_bounds__(256) void scatter_count_kernel(
    const int* __restrict__ src, const int* __restrict__ dst,
    unsigned* __restrict__ cntA, unsigned* __restrict__ cntB,
    unsigned* __restrict__ stagedA, unsigned char* __restrict__ stagedB,
    const float* __restrict__ W0, const float* __restrict__ W1,
    const float* __restrict__ W2, __bf16* __restrict__ Wsp,
    int E, int NB){
  if (blockIdx.x >= B1){
    int gidx = (blockIdx.x - B1)*256 + threadIdx.x;    // 3*16384
    if (gidx < 3*128*128){
      int layer = gidx >> 14, idx = gidx & 16383;
      const float* W = layer == 0 ? W0 : (layer == 1 ? W1 : W2);
      int k = idx >> 7, n = idx & 127;
      float w = W[idx];
      __bf16 h = (__bf16)w;
      __bf16 l = (__bf16)(w - (float)h);
      Wsp[(size_t)layer*2*16384 + n*128 + k] = h;
      Wsp[(size_t)layer*2*16384 + 16384 + n*128 + k] = l;
    }
    return;
  }

  __shared__ unsigned la[NBMAX], lb[NBMAX];
  __shared__ unsigned tsum[256];
  __shared__ unsigned stA[CHUNK_MAX];
  __shared__ unsigned char stB[CHUNK_MAX];

  const int t = threadIdx.x;
  const int blk = blockIdx.x;
  const int chunk = (E + B1 - 1) / B1;
  const int e0 = blk * chunk, e1 = min(e0 + chunk, E);
  const int len = e1 - e0;
  const int strideB = (chunk + 3) & ~3;

  #pragma unroll
  for (int i = t; i < NBMAX; i += 256){ la[i] = 0u; lb[i] = 0u; }
  __syncthreads();
  for (int e = e0 + t; e < e1; e += 256){
    atomicAdd(&la[dst[e] >> 7], 1u);
    atomicAdd(&lb[src[e] >> 7], 1u);
  }
  __syncthreads();

  for (int job = 0; job < 2; job++){
    unsigned* lx = job ? lb : la;
    unsigned* cx = job ? cntB : cntA;
    int b4 = t*4;
    unsigned v0 = lx[b4], v1 = lx[b4+1], v2 = lx[b4+2], v3 = lx[b4+3];
    unsigned s = v0+v1+v2+v3;
    tsum[t] = s;
    __syncthreads();
    for (int off = 1; off < 256; off <<= 1){
      unsigned u = (t >= off) ? tsum[t-off] : 0u;
      __syncthreads();
      tsum[t] += u;
      __syncthreads();
    }
    unsigned run = tsum[t] - s;
    unsigned o0 = run, o1 = run+v0, o2 = run+v0+v1, o3 = run+v0+v1+v2;
    lx[b4] = o0; lx[b4+1] = o1; lx[b4+2] = o2; lx[b4+3] = o3;
    if (b4   < NB) cx[(size_t)blk*NB + b4  ] = o0;
    if (b4+1 < NB) cx[(size_t)blk*NB + b4+1] = o1;
    if (b4+2 < NB) cx[(size_t)blk*NB + b4+2] = o2;
    if (b4+3 < NB) cx[(size_t)blk*NB + b4+3] = o3;
    __syncthreads();
  }

  for (int e = e0 + t; e < e1; e += 256){
    int s = src[e], d = dst[e];
    unsigned pA = atomicAdd(&la[d >> 7], 1u);
    stA[pA] = ((unsigned)(d & 127) << 17) | (unsigned)s;
    unsigned pB = atomicAdd(&lb[s >> 7], 1u);
    stB[pB] = (unsigned char)(s & 127);
  }
  __syncthreads();

  for (int i = t; i < len; i += 256)
    stagedA[(size_t)blk*chunk + i] = stA[i];
  int w4 = (len + 3) >> 2;
  unsigned* gB = (unsigned*)(stagedB + (size_t)blk*strideB);
  for (int i = t; i < w4; i += 256)
    gB[i] = *(unsigned*)&stB[4*i];
}

// totals[job][b] = sum over blk of per-(blk,b) counts (diff of offsets).
__global__ void totals_kernel(const unsigned* __restrict__ cntA,
                              const unsigned* __restrict__ cntB,
                              unsigned* __restrict__ totals, int NB, int E){
  int b = blockIdx.x * 256 + threadIdx.x;
  if (b >= NB) return;
  const unsigned* cx = blockIdx.y ? cntB : cntA;
  const int chunk = (E + B1 - 1) / B1;
  unsigned run = 0;
  for (int blk = 0; blk < B1; blk++){
    int lenb = E - blk*chunk; if (lenb > chunk) lenb = chunk; if (lenb < 0) lenb = 0;
    unsigned cur = cx[(size_t)blk*NB + b];
    unsigned nxt = (b < NB-1) ? cx[(size_t)blk*NB + b + 1] : (unsigned)lenb;
    run += nxt - cur;
  }
  totals[(size_t)blockIdx.y*NB + b] = run;
}

// Single-block exclusive scan of bucket totals -> baseA/baseB (each NB+1).
__global__ void scan_base_kernel(const unsigned* __restrict__ totals,
                                 unsigned* __restrict__ baseA, unsigned* __restrict__ baseB,
                                 int NB, int E){
  __shared__ unsigned s[NBMAX];
  int t = threadIdx.x;  // 1024 threads, NB <= 1024
  for (int job = 0; job < 2; job++){
    unsigned* base = job ? baseB : baseA;
    unsigned x = (t < NB) ? totals[(size_t)job*NB + t] : 0u;
    s[t] = x;
    __syncthreads();
    for (int off = 1; off < NBMAX; off <<= 1){
      unsigned v = (t >= off) ? s[t - off] : 0u;
      __syncthreads();
      s[t] += v;
      __syncthreads();
    }
    if (t < NB) base[t] = s[t] - x;
    if (t == 0) base[NB] = (unsigned)E;
    __syncthreads();
  }
}

// Per-bucket finalize, cooperative segmented gather (R12).
__global__ __launch_bounds__(256) void csr_finalize_kernel(
    const unsigned* __restrict__ stagedA, const unsigned char* __restrict__ stagedB,
    const unsigned* __restrict__ cntA, const unsigned* __restrict__ cntB,
    const unsigned* __restrict__ baseA,
    int* __restrict__ row_ptr, float* __restrict__ inv_dst, float* __restrict__ inv_src,
    int* __restrict__ col, int N, int E, int NB){
  __shared__ unsigned offs[256];
  __shared__ unsigned segbase[257];
  __shared__ unsigned tsum[256];
  __shared__ unsigned edge[BUCKET_MAX];
  __shared__ unsigned sorted[BUCKET_MAX];
  __shared__ unsigned cnt[128];
  __shared__ unsigned scn[128];

  const int b = blockIdx.x, t = threadIdx.x;
  const int node0 = b << 7;
  const int nn = min(128, N - node0);
  const int chunk = (E + B1 - 1) / B1;
  const int strideB = (chunk + 3) & ~3;
  int lenb_t = E - t*chunk; if (lenb_t > chunk) lenb_t = chunk; if (lenb_t < 0) lenb_t = 0;

  // ================= job A: CSR =================
  {
    unsigned o0 = cntA[(size_t)t*NB + b];
    unsigned o1 = (b < NB-1) ? cntA[(size_t)t*NB + b + 1] : (unsigned)lenb_t;
    unsigned len = o1 - o0;
    offs[t] = o0;
    tsum[t] = len;
    __syncthreads();
    for (int off = 1; off < 256; off <<= 1){
      unsigned u = (t >= off) ? tsum[t-off] : 0u;
      __syncthreads();
      tsum[t] += u;
      __syncthreads();
    }
    segbase[t] = tsum[t] - len;
    if (t == 255) segbase[256] = tsum[255];
    __syncthreads();
    int bucketlen = (int)segbase[256];

    for (int idx = t; idx < bucketlen; idx += 256){
      int lo = 0, hi = 255;
      while (lo < hi){ int m = (lo + hi + 1) >> 1; if (segbase[m] <= (unsigned)idx) lo = m; else hi = m - 1; }
      edge[idx] = stagedA[(size_t)lo*chunk + offs[lo] + ((unsigned)idx - segbase[lo])];
    }
    if (t < 128) cnt[t] = 0u;
    __syncthreads();
    for (int idx = t; idx < bucketlen; idx += 256)
      atomicAdd(&cnt[(edge[idx] >> 17) & 127u], 1u);
    __syncthreads();
    unsigned mycnt = (t < 128) ? cnt[t] : 0u;
    if (t < 128) scn[t] = mycnt;
    __syncthreads();
    for (int off = 1; off < 128; off <<= 1){
      unsigned v = (t < 128 && t >= off) ? scn[t - off] : 0u;
      __syncthreads();
      if (t < 128) scn[t] += v;
      __syncthreads();
    }
    int e0 = (int)baseA[b];
    if (t < nn){
      unsigned excl = scn[t] - mycnt;
      row_ptr[node0 + t] = e0 + (int)excl;
      unsigned c = mycnt < 1u ? 1u : mycnt;
      inv_dst[node0 + t] = rsqrtf((float)c);
      cnt[t] = excl;               // bucket-local cursor
    }
    if (b == NB - 1 && t == 0) row_ptr[N] = E;
    __syncthreads();
    for (int idx = t; idx < bucketlen; idx += 256){
      unsigned v = edge[idx];
      unsigned p = atomicAdd(&cnt[(v >> 17) & 127u], 1u);
      sorted[p] = v & 0x1FFFFu;
    }
    __syncthreads();
    for (int idx = t; idx < bucketlen; idx += 256)
      col[e0 + idx] = (int)sorted[idx];
  }

  // ================= job B: out-degree -> inv_src =================
  __syncthreads();
  {
    unsigned o0 = cntB[(size_t)t*NB + b];
    unsigned o1 = (b < NB-1) ? cntB[(size_t)t*NB + b + 1] : (unsigned)lenb_t;
    unsigned len = o1 - o0;
    offs[t] = o0;
    tsum[t] = len;
    __syncthreads();
    for (int off = 1; off < 256; off <<= 1){
      unsigned u = (t >= off) ? tsum[t-off] : 0u;
      __syncthreads();
      tsum[t] += u;
      __syncthreads();
    }
    segbase[t] = tsum[t] - len;
    if (t == 255) segbase[256] = tsum[255];
    if (t < 128) cnt[t] = 0u;
    __syncthreads();
    int bucketlen = (int)segbase[256];
    unsigned char* edgeB = (unsigned char*)edge;
    for (int idx = t; idx < bucketlen; idx += 256){
      int lo = 0, hi = 255;
      while (lo < hi){ int m = (lo + hi + 1) >> 1; if (segbase[m] <= (unsigned)idx) lo = m; else hi = m - 1; }
      edgeB[idx] = stagedB[(size_t)lo*strideB + offs[lo] + ((unsigned)idx - segbase[lo])];
    }
    __syncthreads();
    for (int idx = t; idx < bucketlen; idx += 256)
      atomicAdd(&cnt[edgeB[idx]], 1u);
    __syncthreads();
    if (t < nn){
      unsigned c = cnt[t] < 1u ? 1u : cnt[t];
      inv_src[node0 + t] = rsqrtf((float)c);
    }
  }
}

// ---------------------------------------------------------------------------
// Fused gather + GEMM. One wave per block; block owns 32 output rows.
// Gather: half-wave (32 lanes) per node, lane owns a float4 (verbatim port of
// csr_agg's loop -> identical summation order), packed split-bf16 deposited
// into LDS (row stride 132 dwords = 528B: 16B-aligned, bank-spread).
// GEMM: R13 inner loop, A from LDS, B straight from global (64KB, L2-hot).
// LDS 16.9KB -> 9 blocks(waves)/CU. hs_in and out MUST be distinct buffers
// (cross-block RAW hazard otherwise -- R14's bug).
// ---------------------------------------------------------------------------
template<bool SC>
__global__ __launch_bounds__(64) void fused_agg_gemm_kernel(
    const int* __restrict__ row_ptr, const int* __restrict__ col,
    const float* __restrict__ hs_in, const float* __restrict__ scale,
    const float* __restrict__ inv_dst,
    const __bf16* __restrict__ Whi, const __bf16* __restrict__ Wlo,
    const float* __restrict__ bias, const float* __restrict__ out_scale,
    float* __restrict__ out, int N){
  __shared__ unsigned Apk[32*132];     // 16,896 B packed split-bf16 A tile

  const int lane = threadIdx.x;        // 0..63
  const int half = lane >> 5;          // lanes 0-31: even rows; 32-63: odd
  const int l32  = lane & 31;
  const int row0 = blockIdx.x * 32;

  // ---------------- gather phase ----------------
  for (int i = 0; i < 16; i++){
    int j = i*2 + half;                // wave-local row 0..31
    int node = row0 + j;
    float4 a0 = make_float4(0.f,0.f,0.f,0.f);
    float4 a1 = make_float4(0.f,0.f,0.f,0.f);
    float4 a2 = make_float4(0.f,0.f,0.f,0.f);
    float4 a3 = make_float4(0.f,0.f,0.f,0.f);
    int e = 0, r1 = 0;
    if (node < N){ e = row_ptr[node]; r1 = row_ptr[node+1]; }
    for (; e + 3 < r1; e += 4){
      int s0 = col[e], s1 = col[e+1], s2 = col[e+2], s3 = col[e+3];
      float4 v0 = ((const float4*)(hs_in + (size_t)s0*128))[l32];
      float4 v1 = ((const float4*)(hs_in + (size_t)s1*128))[l32];
      float4 v2 = ((const float4*)(hs_in + (size_t)s2*128))[l32];
      float4 v3 = ((const float4*)(hs_in + (size_t)s3*128))[l32];
      if (SC){
        float c0 = scale[s0], c1 = scale[s1], c2 = scale[s2], c3 = scale[s3];
        v0.x*=c0; v0.y*=c0; v0.z*=c0; v0.w*=c0;
        v1.x*=c1; v1.y*=c1; v1.z*=c1; v1.w*=c1;
        v2.x*=c2; v2.y*=c2; v2.z*=c2; v2.w*=c2;
        v3.x*=c3; v3.y*=c3; v3.z*=c3; v3.w*=c3;
      }
      a0.x += v0.x; a0.y += v0.y; a0.z += v0.z; a0.w += v0.w;
      a1.x += v1.x; a1.y += v1.y; a1.z += v1.z; a1.w += v1.w;
      a2.x += v2.x; a2.y += v2.y; a2.z += v2.z; a2.w += v2.w;
      a3.x += v3.x; a3.y += v3.y; a3.z += v3.z; a3.w += v3.w;
    }
    for (; e < r1; e++){
      int s0 = col[e];
      float4 v0 = ((const float4*)(hs_in + (size_t)s0*128))[l32];
      if (SC){ float c0 = scale[s0]; v0.x*=c0; v0.y*=c0; v0.z*=c0; v0.w*=c0; }
      a0.x += v0.x; a0.y += v0.y; a0.z += v0.z; a0.w += v0.w;
    }
    float idst = (node < N) ? inv_dst[node] : 0.f;
    float rx = ((a0.x + a1.x) + (a2.x + a3.x)) * idst;
    float ry = ((a0.y + a1.y) + (a2.y + a3.y)) * idst;
    float rz = ((a0.z + a1.z) + (a2.z + a3.z)) * idst;
    float rw = ((a0.w + a1.w) + (a2.w + a3.w)) * idst;
    uint4 p;
    p.x = pack_split(rx); p.y = pack_split(ry);
    p.z = pack_split(rz); p.w = pack_split(rw);
    *(uint4*)&Apk[j*132 + l32*4] = p;
  }
  __syncthreads();

  // ---------------- GEMM phase ----------------
  const int q  = lane >> 4;
  const int mn = lane & 15;

  f32x4 acc[2][8];
  #pragma unroll
  for (int mt = 0; mt < 2; mt++)
    #pragma unroll
    for (int nt = 0; nt < 8; nt++)
      acc[mt][nt] = (f32x4){0.f,0.f,0.f,0.f};

  #pragma unroll
  for (int kc = 0; kc < 4; kc++){
    bf16x8 ah[2], al[2];
    #pragma unroll
    for (int mt = 0; mt < 2; mt++){
      const unsigned* ap = &Apk[(mt*16 + mn)*132 + kc*32 + q*8];
      uint4 x0 = *(const uint4*)ap;
      uint4 x1 = *(const uint4*)(ap + 4);
      unsigned v[8] = {x0.x, x0.y, x0.z, x0.w, x1.x, x1.y, x1.z, x1.w};
      #pragma unroll
      for (int jj = 0; jj < 8; jj++){
        ah[mt][jj] = bits_to_bf16((unsigned short)(v[jj] >> 16));
        al[mt][jj] = bits_to_bf16((unsigned short)(v[jj] & 0xFFFFu));
      }
    }
    #pragma unroll
    for (int nt = 0; nt < 8; nt++){
      const __bf16* bhp = Whi + (nt*16 + mn)*128 + kc*32 + q*8;
      const __bf16* blp = Wlo + (nt*16 + mn)*128 + kc*32 + q*8;
      bf16x8 bh = *(const bf16x8*)bhp;
      bf16x8 bl = *(const bf16x8*)blp;
      #pragma unroll
      for (int mt = 0; mt < 2; mt++){
        acc[mt][nt] = __builtin_amdgcn_mfma_f32_16x16x32_bf16(al[mt], bh, acc[mt][nt], 0, 0, 0);
        acc[mt][nt] = __builtin_amdgcn_mfma_f32_16x16x32_bf16(ah[mt], bl, acc[mt][nt], 0, 0, 0);
        acc[mt][nt] = __builtin_amdgcn_mfma_f32_16x16x32_bf16(ah[mt], bh, acc[mt][nt], 0, 0, 0);
      }
    }
  }

  // ---------------- epilogue ----------------
  #pragma unroll
  for (int mt = 0; mt < 2; mt++){
    #pragma unroll
    for (int r = 0; r < 4; r++){
      int gm = row0 + mt*16 + q*4 + r;
      if (gm < N){
        float osc = out_scale ? out_scale[gm] : 1.f;
        #pragma unroll
        for (int nt = 0; nt < 8; nt++){
          float v = acc[mt][nt][r] + bias[nt*16 + mn];
          v = fmaxf(v, 0.f) * osc;
          out[(size_t)gm*128 + nt*16 + mn] = v;
        }
      }
    }
  }
}

// Fused head: avg-pool (8 graphs/block) + MLP 128->512->256->1, all in LDS.
__global__ __launch_bounds__(256) void head_kernel(
    const float* __restrict__ h, const int* __restrict__ gid,
    const float* __restrict__ Wm0, const float* __restrict__ bm0,
    const float* __restrict__ Wm1, const float* __restrict__ bm1,
    const float* __restrict__ Wm2, const float* __restrict__ bm2,
    float* __restrict__ out, int N, int G){
  __shared__ float embL[8][128];
  __shared__ float x1L[8][512];
  __shared__ float x2L[8][256];

  const int t = threadIdx.x;
  const int wave = t >> 6, lane = t & 63;
  const int g0 = blockIdx.x * 8;

  for (int gg = 0; gg < 2; gg++){
    int gl = wave*2 + gg;
    int g = g0 + gl;
    float ax = 0.f, ay = 0.f;
    int start = 0, end = 0;
    if (g < G){
      int lo = 0, hi = N;
      while (lo < hi){ int mid = (lo + hi) >> 1; if (gid[mid] < g) lo = mid + 1; else hi = mid; }
      start = lo;
      hi = N;
      while (lo < hi){ int mid = (lo + hi) >> 1; if (gid[mid] <= g) lo = mid + 1; else hi = mid; }
      end = lo;
      for (int n = start; n < end; n++){
        float2 v = ((const float2*)(h + (size_t)n*128))[lane];
        ax += v.x; ay += v.y;
      }
    }
    int c = end - start; if (c < 1) c = 1;
    float invc = 1.0f / (float)c;
    embL[gl][2*lane]   = ax * invc;
    embL[gl][2*lane+1] = ay * invc;
  }
  __syncthreads();

  {
    float acc[8][2];
    #pragma unroll
    for (int g = 0; g < 8; g++){ acc[g][0] = 0.f; acc[g][1] = 0.f; }
    for (int k = 0; k < 128; k++){
      float w0 = Wm0[(size_t)k*512 + t];
      float w1 = Wm0[(size_t)k*512 + t + 256];
      #pragma unroll
      for (int g = 0; g < 8; g++){
        float e = embL[g][k];
        acc[g][0] = fmaf(e, w0, acc[g][0]);
        acc[g][1] = fmaf(e, w1, acc[g][1]);
      }
    }
    float b0v = bm0[t], b1v = bm0[t + 256];
    #pragma unroll
    for (int g = 0; g < 8; g++){
      x1L[g][t]       = fmaxf(acc[g][0] + b0v, 0.f);
      x1L[g][t + 256] = fmaxf(acc[g][1] + b1v, 0.f);
    }
  }
  __syncthreads();

  {
    float acc[8];
    #pragma unroll
    for (int g = 0; g < 8; g++) acc[g] = 0.f;
    for (int k = 0; k < 512; k++){
      float w = Wm1[(size_t)k*256 + t];
      #pragma unroll
      for (int g = 0; g < 8; g++)
        acc[g] = fmaf(x1L[g][k], w, acc[g]);
    }
    float bv = bm1[t];
    #pragma unroll
    for (int g = 0; g < 8; g++)
      x2L[g][t] = fmaxf(acc[g] + bv, 0.f);
  }
  __syncthreads();

  {
    int g = t >> 5;
    int c = t & 31;
    float s = 0.f;
    for (int i = c; i < 256; i += 32)
      s = fmaf(x2L[g][i], Wm2[i], s);
    for (int off = 16; off > 0; off >>= 1) s += __shfl_down(s, off, 32);
    if (c == 0 && (g0 + g) < G) out[g0 + g] = s + bm2[0];
  }
}

extern "C" void kernel_launch(void* const* d_in, const int* in_sizes, int n_in,
                              void* d_out, int out_size, void* d_ws, size_t ws_size,
                              hipStream_t stream){
  const float* feats = (const float*)d_in[0];
  const int*   src   = (const int*)d_in[1];
  const int*   dst   = (const int*)d_in[2];
  const int*   gid   = (const int*)d_in[3];
  const float* W0 = (const float*)d_in[4];   const float* b0 = (const float*)d_in[5];
  const float* W1 = (const float*)d_in[6];   const float* b1 = (const float*)d_in[7];
  const float* W2 = (const float*)d_in[8];   const float* b2 = (const float*)d_in[9];
  const float* Wm0 = (const float*)d_in[10]; const float* bm0 = (const float*)d_in[11];
  const float* Wm1 = (const float*)d_in[12]; const float* bm1 = (const float*)d_in[13];
  const float* Wm2 = (const float*)d_in[14]; const float* bm2 = (const float*)d_in[15];
  float* out = (float*)d_out;

  const int E   = in_sizes[1];
  const int N   = in_sizes[3];
  const int G   = out_size;
  const int NB  = ceil_div(N, 128);
  const int chunk = ceil_div(E, B1);
  const int strideB = (chunk + 3) & ~3;

  char* ws = (char*)d_ws;
  size_t off = 0;
  auto carve = [&](size_t bytes) -> char* {
    off = (off + 255) & ~(size_t)255;
    char* p = ws + off; off += bytes; return p;
  };
  float* inv_src = (float*)carve((size_t)N*4);
  float* inv_dst = (float*)carve((size_t)N*4);
  int* row_ptr = (int*)carve((size_t)(N+1)*4);
  int* col     = (int*)carve((size_t)E*4);
  __bf16* Wsp = (__bf16*)carve(6*128*128*2);   // hi0,lo0,hi1,lo1,hi2,lo2
  float* hsA = (float*)carve((size_t)N*128*4);
  float* hsB = (float*)carve((size_t)N*128*4);

  // CSR-build temporaries alias hsB (dead until layer 1 writes it).
  unsigned* T = (unsigned*)hsB;
  unsigned* cntA   = T;
  unsigned* cntB   = cntA + (size_t)B1*NB;
  unsigned* totals = cntB + (size_t)B1*NB;
  unsigned* baseA  = totals + 2*(size_t)NB;
  unsigned* baseB  = baseA + (NB+1);
  unsigned* stagedA = baseB + (NB+1);
  unsigned char* stagedB = (unsigned char*)(stagedA + (size_t)B1*chunk);

  scatter_count_kernel<<<B1 + WPREP_BLOCKS, 256, 0, stream>>>(
      src, dst, cntA, cntB, stagedA, stagedB, W0, W1, W2, Wsp, E, NB);
  totals_kernel<<<dim3(ceil_div(NB,256), 2), 256, 0, stream>>>(cntA, cntB, totals, NB, E);
  scan_base_kernel<<<1, NBMAX, 0, stream>>>(totals, baseA, baseB, NB, E);
  csr_finalize_kernel<<<NB, 256, 0, stream>>>(stagedA, stagedB, cntA, cntB, baseA,
                                              row_ptr, inv_dst, inv_src, col, N, E, NB);

  const int fgrid = ceil_div(N, 32);
  __bf16 *Whi0 = Wsp,            *Wlo0 = Wsp + 16384;
  __bf16 *Whi1 = Wsp + 2*16384,  *Wlo1 = Wsp + 3*16384;
  __bf16 *Whi2 = Wsp + 4*16384,  *Wlo2 = Wsp + 5*16384;
  // layer 0: feats -> hsA (gather scales by inv_src; epilogue pre-scales next
  // layer's src mult via out_scale=inv_src)
  fused_agg_gemm_kernel<true><<<fgrid, 64, 0, stream>>>(
      row_ptr, col, feats, inv_src, inv_dst, Whi0, Wlo0, b0, inv_src, hsA, N);
  // layer 1: hsA -> hsB
  fused_agg_gemm_kernel<false><<<fgrid, 64, 0, stream>>>(
      row_ptr, col, hsA, nullptr, inv_dst, Whi1, Wlo1, b1, inv_src, hsB, N);
  // layer 2: hsB -> hsA (no out_scale)
  fused_agg_gemm_kernel<false><<<fgrid, 64, 0, stream>>>(
      row_ptr, col, hsB, nullptr, inv_dst, Whi2, Wlo2, b2, nullptr, hsA, N);
  // fused pool + MLP head
  head_kernel<<<ceil_div(G,8), 256, 0, stream>>>(hsA, gid, Wm0, bm0, Wm1, bm1, Wm2, bm2, out, N, G);
}

// Round 3
// 701.431 us; speedup vs baseline: 1.2937x; 1.2937x over previous
//
#include <hip/hip_runtime.h>

// ---------------------------------------------------------------------------
// GNN: 3x GraphConv (norm='both') + avg-pool + MLP(128->512->256->1), fp32.
// R16: fused gather+GEMM with occupancy restored. R15's 1-wave blocks
// (16.9KB LDS) gave 17% occupancy -> gather latency-bound at 1.97 TB/s
// (csr_agg sustained 3.8 TB/s at 76%). Now: 512-thread blocks (8 waves),
// 64-row tile, 33.8KB LDS -> 4 blocks/CU; GEMM acc shrinks to [2][2]/wave
// (wave = 32row x 32col sub-tile) so VGPR ~60 -> 24-32 waves/CU. Gather
// loop body is still a verbatim csr_agg port (bit-identical per-row sums).
// Layers ping-pong hsA <-> hsB (R14's in-place RAW race stays fixed).
// ---------------------------------------------------------------------------

static inline int ceil_div(int a, int b){ return (a + b - 1) / b; }

#define B1 256          // scatter blocks == segments per bucket
#define NBMAX 1024      // max buckets (N <= 131072; src ids fit in 17 bits)
#define CHUNK_MAX 7168  // max edges per scatter block (E <= B1*CHUNK_MAX)
#define BUCKET_MAX 4096 // max edges per bucket (mean ~2048)
#define WPREP_BLOCKS 192

typedef __bf16 bf16x8 __attribute__((ext_vector_type(8)));
typedef float  f32x4  __attribute__((ext_vector_type(4)));

static __device__ inline __bf16 bits_to_bf16(unsigned short u){
  union { unsigned short u; __bf16 b; } x; x.u = u; return x.b;
}
static __device__ inline unsigned short bf16_bits(__bf16 b){
  union { __bf16 b; unsigned short u; } x; x.b = b; return x.u;
}
static __device__ inline unsigned pack_split(float s){
  __bf16 h = (__bf16)s;
  __bf16 l = (__bf16)(s - (float)h);
  return ((unsigned)bf16_bits(h) << 16) | (unsigned)bf16_bits(l);
}

// One-pass bucketed counting sort, block-local staging, coalesced flush.
// Also hosts wprep on blocks >= B1 (W fp32 -> split-bf16 [n][k]).
__global__ __launch_bounds__(256) void scatter_count_kernel(
    const int* __restrict__ src, const int* __restrict__ dst,
    unsigned* __restrict__ cntA, unsigned* __restrict__ cntB,
    unsigned* __restrict__ stagedA, unsigned char* __restrict__ stagedB,
    const float* __restrict__ W0, const float* __restrict__ W1,
    const float* __restrict__ W2, __bf16* __restrict__ Wsp,
    int E, int NB){
  if (blockIdx.x >= B1){
    int gidx = (blockIdx.x - B1)*256 + threadIdx.x;    // 3*16384
    if (gidx < 3*128*128){
      int layer = gidx >> 14, idx = gidx & 16383;
      const float* W = layer == 0 ? W0 : (layer == 1 ? W1 : W2);
      int k = idx >> 7, n = idx & 127;
      float w = W[idx];
      __bf16 h = (__bf16)w;
      __bf16 l = (__bf16)(w - (float)h);
      Wsp[(size_t)layer*2*16384 + n*128 + k] = h;
      Wsp[(size_t)layer*2*16384 + 16384 + n*128 + k] = l;
    }
    return;
  }

  __shared__ unsigned la[NBMAX], lb[NBMAX];
  __shared__ unsigned tsum[256];
  __shared__ unsigned stA[CHUNK_MAX];
  __shared__ unsigned char stB[CHUNK_MAX];

  const int t = threadIdx.x;
  const int blk = blockIdx.x;
  const int chunk = (E + B1 - 1) / B1;
  const int e0 = blk * chunk, e1 = min(e0 + chunk, E);
  const int len = e1 - e0;
  const int strideB = (chunk + 3) & ~3;

  #pragma unroll
  for (int i = t; i < NBMAX; i += 256){ la[i] = 0u; lb[i] = 0u; }
  __syncthreads();
  for (int e = e0 + t; e < e1; e += 256){
    atomicAdd(&la[dst[e] >> 7], 1u);
    atomicAdd(&lb[src[e] >> 7], 1u);
  }
  __syncthreads();

  for (int job = 0; job < 2; job++){
    unsigned* lx = job ? lb : la;
    unsigned* cx = job ? cntB : cntA;
    int b4 = t*4;
    unsigned v0 = lx[b4], v1 = lx[b4+1], v2 = lx[b4+2], v3 = lx[b4+3];
    unsigned s = v0+v1+v2+v3;
    tsum[t] = s;
    __syncthreads();
    for (int off = 1; off < 256; off <<= 1){
      unsigned u = (t >= off) ? tsum[t-off] : 0u;
      __syncthreads();
      tsum[t] += u;
      __syncthreads();
    }
    unsigned run = tsum[t] - s;
    unsigned o0 = run, o1 = run+v0, o2 = run+v0+v1, o3 = run+v0+v1+v2;
    lx[b4] = o0; lx[b4+1] = o1; lx[b4+2] = o2; lx[b4+3] = o3;
    if (b4   < NB) cx[(size_t)blk*NB + b4  ] = o0;
    if (b4+1 < NB) cx[(size_t)blk*NB + b4+1] = o1;
    if (b4+2 < NB) cx[(size_t)blk*NB + b4+2] = o2;
    if (b4+3 < NB) cx[(size_t)blk*NB + b4+3] = o3;
    __syncthreads();
  }

  for (int e = e0 + t; e < e1; e += 256){
    int s = src[e], d = dst[e];
    unsigned pA = atomicAdd(&la[d >> 7], 1u);
    stA[pA] = ((unsigned)(d & 127) << 17) | (unsigned)s;
    unsigned pB = atomicAdd(&lb[s >> 7], 1u);
    stB[pB] = (unsigned char)(s & 127);
  }
  __syncthreads();

  for (int i = t; i < len; i += 256)
    stagedA[(size_t)blk*chunk + i] = stA[i];
  int w4 = (len + 3) >> 2;
  unsigned* gB = (unsigned*)(stagedB + (size_t)blk*strideB);
  for (int i = t; i < w4; i += 256)
    gB[i] = *(unsigned*)&stB[4*i];
}

// totals[job][b] = sum over blk of per-(blk,b) counts (diff of offsets).
__global__ void totals_kernel(const unsigned* __restrict__ cntA,
                              const unsigned* __restrict__ cntB,
                              unsigned* __restrict__ totals, int NB, int E){
  int b = blockIdx.x * 256 + threadIdx.x;
  if (b >= NB) return;
  const unsigned* cx = blockIdx.y ? cntB : cntA;
  const int chunk = (E + B1 - 1) / B1;
  unsigned run = 0;
  for (int blk = 0; blk < B1; blk++){
    int lenb = E - blk*chunk; if (lenb > chunk) lenb = chunk; if (lenb < 0) lenb = 0;
    unsigned cur = cx[(size_t)blk*NB + b];
    unsigned nxt = (b < NB-1) ? cx[(size_t)blk*NB + b + 1] : (unsigned)lenb;
    run += nxt - cur;
  }
  totals[(size_t)blockIdx.y*NB + b] = run;
}

// Single-block exclusive scan of bucket totals -> baseA/baseB (each NB+1).
__global__ void scan_base_kernel(const unsigned* __restrict__ totals,
                                 unsigned* __restrict__ baseA, unsigned* __restrict__ baseB,
                                 int NB, int E){
  __shared__ unsigned s[NBMAX];
  int t = threadIdx.x;  // 1024 threads, NB <= 1024
  for (int job = 0; job < 2; job++){
    unsigned* base = job ? baseB : baseA;
    unsigned x = (t < NB) ? totals[(size_t)job*NB + t] : 0u;
    s[t] = x;
    __syncthreads();
    for (int off = 1; off < NBMAX; off <<= 1){
      unsigned v = (t >= off) ? s[t - off] : 0u;
      __syncthreads();
      s[t] += v;
      __syncthreads();
    }
    if (t < NB) base[t] = s[t] - x;
    if (t == 0) base[NB] = (unsigned)E;
    __syncthreads();
  }
}

// Per-bucket finalize, cooperative segmented gather (R12).
__global__ __launch_bounds__(256) void csr_finalize_kernel(
    const unsigned* __restrict__ stagedA, const unsigned char* __restrict__ stagedB,
    const unsigned* __restrict__ cntA, const unsigned* __restrict__ cntB,
    const unsigned* __restrict__ baseA,
    int* __restrict__ row_ptr, float* __restrict__ inv_dst, float* __restrict__ inv_src,
    int* __restrict__ col, int N, int E, int NB){
  __shared__ unsigned offs[256];
  __shared__ unsigned segbase[257];
  __shared__ unsigned tsum[256];
  __shared__ unsigned edge[BUCKET_MAX];
  __shared__ unsigned sorted[BUCKET_MAX];
  __shared__ unsigned cnt[128];
  __shared__ unsigned scn[128];

  const int b = blockIdx.x, t = threadIdx.x;
  const int node0 = b << 7;
  const int nn = min(128, N - node0);
  const int chunk = (E + B1 - 1) / B1;
  const int strideB = (chunk + 3) & ~3;
  int lenb_t = E - t*chunk; if (lenb_t > chunk) lenb_t = chunk; if (lenb_t < 0) lenb_t = 0;

  // ================= job A: CSR =================
  {
    unsigned o0 = cntA[(size_t)t*NB + b];
    unsigned o1 = (b < NB-1) ? cntA[(size_t)t*NB + b + 1] : (unsigned)lenb_t;
    unsigned len = o1 - o0;
    offs[t] = o0;
    tsum[t] = len;
    __syncthreads();
    for (int off = 1; off < 256; off <<= 1){
      unsigned u = (t >= off) ? tsum[t-off] : 0u;
      __syncthreads();
      tsum[t] += u;
      __syncthreads();
    }
    segbase[t] = tsum[t] - len;
    if (t == 255) segbase[256] = tsum[255];
    __syncthreads();
    int bucketlen = (int)segbase[256];

    for (int idx = t; idx < bucketlen; idx += 256){
      int lo = 0, hi = 255;
      while (lo < hi){ int m = (lo + hi + 1) >> 1; if (segbase[m] <= (unsigned)idx) lo = m; else hi = m - 1; }
      edge[idx] = stagedA[(size_t)lo*chunk + offs[lo] + ((unsigned)idx - segbase[lo])];
    }
    if (t < 128) cnt[t] = 0u;
    __syncthreads();
    for (int idx = t; idx < bucketlen; idx += 256)
      atomicAdd(&cnt[(edge[idx] >> 17) & 127u], 1u);
    __syncthreads();
    unsigned mycnt = (t < 128) ? cnt[t] : 0u;
    if (t < 128) scn[t] = mycnt;
    __syncthreads();
    for (int off = 1; off < 128; off <<= 1){
      unsigned v = (t < 128 && t >= off) ? scn[t - off] : 0u;
      __syncthreads();
      if (t < 128) scn[t] += v;
      __syncthreads();
    }
    int e0 = (int)baseA[b];
    if (t < nn){
      unsigned excl = scn[t] - mycnt;
      row_ptr[node0 + t] = e0 + (int)excl;
      unsigned c = mycnt < 1u ? 1u : mycnt;
      inv_dst[node0 + t] = rsqrtf((float)c);
      cnt[t] = excl;               // bucket-local cursor
    }
    if (b == NB - 1 && t == 0) row_ptr[N] = E;
    __syncthreads();
    for (int idx = t; idx < bucketlen; idx += 256){
      unsigned v = edge[idx];
      unsigned p = atomicAdd(&cnt[(v >> 17) & 127u], 1u);
      sorted[p] = v & 0x1FFFFu;
    }
    __syncthreads();
    for (int idx = t; idx < bucketlen; idx += 256)
      col[e0 + idx] = (int)sorted[idx];
  }

  // ================= job B: out-degree -> inv_src =================
  __syncthreads();
  {
    unsigned o0 = cntB[(size_t)t*NB + b];
    unsigned o1 = (b < NB-1) ? cntB[(size_t)t*NB + b + 1] : (unsigned)lenb_t;
    unsigned len = o1 - o0;
    offs[t] = o0;
    tsum[t] = len;
    __syncthreads();
    for (int off = 1; off < 256; off <<= 1){
      unsigned u = (t >= off) ? tsum[t-off] : 0u;
      __syncthreads();
      tsum[t] += u;
      __syncthreads();
    }
    segbase[t] = tsum[t] - len;
    if (t == 255) segbase[256] = tsum[255];
    if (t < 128) cnt[t] = 0u;
    __syncthreads();
    int bucketlen = (int)segbase[256];
    unsigned char* edgeB = (unsigned char*)edge;
    for (int idx = t; idx < bucketlen; idx += 256){
      int lo = 0, hi = 255;
      while (lo < hi){ int m = (lo + hi + 1) >> 1; if (segbase[m] <= (unsigned)idx) lo = m; else hi = m - 1; }
      edgeB[idx] = stagedB[(size_t)lo*strideB + offs[lo] + ((unsigned)idx - segbase[lo])];
    }
    __syncthreads();
    for (int idx = t; idx < bucketlen; idx += 256)
      atomicAdd(&cnt[edgeB[idx]], 1u);
    __syncthreads();
    if (t < nn){
      unsigned c = cnt[t] < 1u ? 1u : cnt[t];
      inv_src[node0 + t] = rsqrtf((float)c);
    }
  }
}

// ---------------------------------------------------------------------------
// Fused gather + GEMM. 512 threads (8 waves) per block; block owns 64 rows.
// Gather: 16 half-waves x 4 rows each, lane owns a float4 (verbatim csr_agg
// loop -> bit-identical per-row sums), packed split-bf16 into LDS (row
// stride 132 dwords: 16B-aligned, bank-rotated). GEMM: wave w computes the
// 32row x 32col sub-tile (mg = w>>2, ng = w&3), acc[2][2]; A from LDS, B
// from global (64KB, L2-hot). LDS 33.8KB -> 4 blocks/CU; VGPR ~60 ->
// 24-32 waves/CU (csr_agg's 3.8 TB/s needed ~76% occupancy).
// hs_in and out MUST be distinct buffers (R14's cross-block RAW race).
// ---------------------------------------------------------------------------
template<bool SC>
__global__ __launch_bounds__(512) void fused_agg_gemm_kernel(
    const int* __restrict__ row_ptr, const int* __restrict__ col,
    const float* __restrict__ hs_in, const float* __restrict__ scale,
    const float* __restrict__ inv_dst,
    const __bf16* __restrict__ Whi, const __bf16* __restrict__ Wlo,
    const float* __restrict__ bias, const float* __restrict__ out_scale,
    float* __restrict__ out, int N){
  __shared__ unsigned Apk[64*132];     // 33,792 B packed split-bf16 A tile

  const int tid  = threadIdx.x;        // 0..511
  const int hw   = tid >> 5;           // half-wave 0..15
  const int l32  = tid & 31;
  const int row0 = blockIdx.x * 64;

  // ---------------- gather phase ----------------
  for (int i = 0; i < 4; i++){
    int j = hw*4 + i;                  // block-local row 0..63
    int node = row0 + j;
    float4 a0 = make_float4(0.f,0.f,0.f,0.f);
    float4 a1 = make_float4(0.f,0.f,0.f,0.f);
    float4 a2 = make_float4(0.f,0.f,0.f,0.f);
    float4 a3 = make_float4(0.f,0.f,0.f,0.f);
    int e = 0, r1 = 0;
    if (node < N){ e = row_ptr[node]; r1 = row_ptr[node+1]; }
    for (; e + 3 < r1; e += 4){
      int s0 = col[e], s1 = col[e+1], s2 = col[e+2], s3 = col[e+3];
      float4 v0 = ((const float4*)(hs_in + (size_t)s0*128))[l32];
      float4 v1 = ((const float4*)(hs_in + (size_t)s1*128))[l32];
      float4 v2 = ((const float4*)(hs_in + (size_t)s2*128))[l32];
      float4 v3 = ((const float4*)(hs_in + (size_t)s3*128))[l32];
      if (SC){
        float c0 = scale[s0], c1 = scale[s1], c2 = scale[s2], c3 = scale[s3];
        v0.x*=c0; v0.y*=c0; v0.z*=c0; v0.w*=c0;
        v1.x*=c1; v1.y*=c1; v1.z*=c1; v1.w*=c1;
        v2.x*=c2; v2.y*=c2; v2.z*=c2; v2.w*=c2;
        v3.x*=c3; v3.y*=c3; v3.z*=c3; v3.w*=c3;
      }
      a0.x += v0.x; a0.y += v0.y; a0.z += v0.z; a0.w += v0.w;
      a1.x += v1.x; a1.y += v1.y; a1.z += v1.z; a1.w += v1.w;
      a2.x += v2.x; a2.y += v2.y; a2.z += v2.z; a2.w += v2.w;
      a3.x += v3.x; a3.y += v3.y; a3.z += v3.z; a3.w += v3.w;
    }
    for (; e < r1; e++){
      int s0 = col[e];
      float4 v0 = ((const float4*)(hs_in + (size_t)s0*128))[l32];
      if (SC){ float c0 = scale[s0]; v0.x*=c0; v0.y*=c0; v0.z*=c0; v0.w*=c0; }
      a0.x += v0.x; a0.y += v0.y; a0.z += v0.z; a0.w += v0.w;
    }
    float idst = (node < N) ? inv_dst[node] : 0.f;
    float rx = ((a0.x + a1.x) + (a2.x + a3.x)) * idst;
    float ry = ((a0.y + a1.y) + (a2.y + a3.y)) * idst;
    float rz = ((a0.z + a1.z) + (a2.z + a3.z)) * idst;
    float rw = ((a0.w + a1.w) + (a2.w + a3.w)) * idst;
    uint4 p;
    p.x = pack_split(rx); p.y = pack_split(ry);
    p.z = pack_split(rz); p.w = pack_split(rw);
    *(uint4*)&Apk[j*132 + l32*4] = p;
  }
  __syncthreads();

  // ---------------- GEMM phase ----------------
  const int wv   = tid >> 6;           // wave 0..7
  const int lane = tid & 63;
  const int q    = lane >> 4;
  const int mn   = lane & 15;
  const int mg   = wv >> 2;            // m-group: rows mg*32 .. +32
  const int ng   = wv & 3;             // n-group: cols ng*32 .. +32

  f32x4 acc[2][2];
  #pragma unroll
  for (int mt = 0; mt < 2; mt++)
    #pragma unroll
    for (int nt = 0; nt < 2; nt++)
      acc[mt][nt] = (f32x4){0.f,0.f,0.f,0.f};

  #pragma unroll
  for (int kc = 0; kc < 4; kc++){
    bf16x8 ah[2], al[2];
    #pragma unroll
    for (int mt = 0; mt < 2; mt++){
      const unsigned* ap = &Apk[(mg*32 + mt*16 + mn)*132 + kc*32 + q*8];
      uint4 x0 = *(const uint4*)ap;
      uint4 x1 = *(const uint4*)(ap + 4);
      unsigned v[8] = {x0.x, x0.y, x0.z, x0.w, x1.x, x1.y, x1.z, x1.w};
      #pragma unroll
      for (int jj = 0; jj < 8; jj++){
        ah[mt][jj] = bits_to_bf16((unsigned short)(v[jj] >> 16));
        al[mt][jj] = bits_to_bf16((unsigned short)(v[jj] & 0xFFFFu));
      }
    }
    #pragma unroll
    for (int nt = 0; nt < 2; nt++){
      int n = ng*32 + nt*16 + mn;
      const __bf16* bhp = Whi + (size_t)n*128 + kc*32 + q*8;
      const __bf16* blp = Wlo + (size_t)n*128 + kc*32 + q*8;
      bf16x8 bh = *(const bf16x8*)bhp;
      bf16x8 bl = *(const bf16x8*)blp;
      #pragma unroll
      for (int mt = 0; mt < 2; mt++){
        acc[mt][nt] = __builtin_amdgcn_mfma_f32_16x16x32_bf16(al[mt], bh, acc[mt][nt], 0, 0, 0);
        acc[mt][nt] = __builtin_amdgcn_mfma_f32_16x16x32_bf16(ah[mt], bl, acc[mt][nt], 0, 0, 0);
        acc[mt][nt] = __builtin_amdgcn_mfma_f32_16x16x32_bf16(ah[mt], bh, acc[mt][nt], 0, 0, 0);
      }
    }
  }

  // ---------------- epilogue ----------------
  #pragma unroll
  for (int mt = 0; mt < 2; mt++){
    #pragma unroll
    for (int r = 0; r < 4; r++){
      int gm = row0 + mg*32 + mt*16 + q*4 + r;
      if (gm < N){
        float osc = out_scale ? out_scale[gm] : 1.f;
        #pragma unroll
        for (int nt = 0; nt < 2; nt++){
          int n = ng*32 + nt*16 + mn;
          float v = acc[mt][nt][r] + bias[n];
          v = fmaxf(v, 0.f) * osc;
          out[(size_t)gm*128 + n] = v;
        }
      }
    }
  }
}

// Fused head: avg-pool (8 graphs/block) + MLP 128->512->256->1, all in LDS.
__global__ __launch_bounds__(256) void head_kernel(
    const float* __restrict__ h, const int* __restrict__ gid,
    const float* __restrict__ Wm0, const float* __restrict__ bm0,
    const float* __restrict__ Wm1, const float* __restrict__ bm1,
    const float* __restrict__ Wm2, const float* __restrict__ bm2,
    float* __restrict__ out, int N, int G){
  __shared__ float embL[8][128];
  __shared__ float x1L[8][512];
  __shared__ float x2L[8][256];

  const int t = threadIdx.x;
  const int wave = t >> 6, lane = t & 63;
  const int g0 = blockIdx.x * 8;

  for (int gg = 0; gg < 2; gg++){
    int gl = wave*2 + gg;
    int g = g0 + gl;
    float ax = 0.f, ay = 0.f;
    int start = 0, end = 0;
    if (g < G){
      int lo = 0, hi = N;
      while (lo < hi){ int mid = (lo + hi) >> 1; if (gid[mid] < g) lo = mid + 1; else hi = mid; }
      start = lo;
      hi = N;
      while (lo < hi){ int mid = (lo + hi) >> 1; if (gid[mid] <= g) lo = mid + 1; else hi = mid; }
      end = lo;
      for (int n = start; n < end; n++){
        float2 v = ((const float2*)(h + (size_t)n*128))[lane];
        ax += v.x; ay += v.y;
      }
    }
    int c = end - start; if (c < 1) c = 1;
    float invc = 1.0f / (float)c;
    embL[gl][2*lane]   = ax * invc;
    embL[gl][2*lane+1] = ay * invc;
  }
  __syncthreads();

  {
    float acc[8][2];
    #pragma unroll
    for (int g = 0; g < 8; g++){ acc[g][0] = 0.f; acc[g][1] = 0.f; }
    for (int k = 0; k < 128; k++){
      float w0 = Wm0[(size_t)k*512 + t];
      float w1 = Wm0[(size_t)k*512 + t + 256];
      #pragma unroll
      for (int g = 0; g < 8; g++){
        float e = embL[g][k];
        acc[g][0] = fmaf(e, w0, acc[g][0]);
        acc[g][1] = fmaf(e, w1, acc[g][1]);
      }
    }
    float b0v = bm0[t], b1v = bm0[t + 256];
    #pragma unroll
    for (int g = 0; g < 8; g++){
      x1L[g][t]       = fmaxf(acc[g][0] + b0v, 0.f);
      x1L[g][t + 256] = fmaxf(acc[g][1] + b1v, 0.f);
    }
  }
  __syncthreads();

  {
    float acc[8];
    #pragma unroll
    for (int g = 0; g < 8; g++) acc[g] = 0.f;
    for (int k = 0; k < 512; k++){
      float w = Wm1[(size_t)k*256 + t];
      #pragma unroll
      for (int g = 0; g < 8; g++)
        acc[g] = fmaf(x1L[g][k], w, acc[g]);
    }
    float bv = bm1[t];
    #pragma unroll
    for (int g = 0; g < 8; g++)
      x2L[g][t] = fmaxf(acc[g] + bv, 0.f);
  }
  __syncthreads();

  {
    int g = t >> 5;
    int c = t & 31;
    float s = 0.f;
    for (int i = c; i < 256; i += 32)
      s = fmaf(x2L[g][i], Wm2[i], s);
    for (int off = 16; off > 0; off >>= 1) s += __shfl_down(s, off, 32);
    if (c == 0 && (g0 + g) < G) out[g0 + g] = s + bm2[0];
  }
}

extern "C" void kernel_launch(void* const* d_in, const int* in_sizes, int n_in,
                              void* d_out, int out_size, void* d_ws, size_t ws_size,
                              hipStream_t stream){
  const float* feats = (const float*)d_in[0];
  const int*   src   = (const int*)d_in[1];
  const int*   dst   = (const int*)d_in[2];
  const int*   gid   = (const int*)d_in[3];
  const float* W0 = (const float*)d_in[4];   const float* b0 = (const float*)d_in[5];
  const float* W1 = (const float*)d_in[6];   const float* b1 = (const float*)d_in[7];
  const float* W2 = (const float*)d_in[8];   const float* b2 = (const float*)d_in[9];
  const float* Wm0 = (const float*)d_in[10]; const float* bm0 = (const float*)d_in[11];
  const float* Wm1 = (const float*)d_in[12]; const float* bm1 = (const float*)d_in[13];
  const float* Wm2 = (const float*)d_in[14]; const float* bm2 = (const float*)d_in[15];
  float* out = (float*)d_out;

  const int E   = in_sizes[1];
  const int N   = in_sizes[3];
  const int G   = out_size;
  const int NB  = ceil_div(N, 128);
  const int chunk = ceil_div(E, B1);
  const int strideB = (chunk + 3) & ~3;

  char* ws = (char*)d_ws;
  size_t off = 0;
  auto carve = [&](size_t bytes) -> char* {
    off = (off + 255) & ~(size_t)255;
    char* p = ws + off; off += bytes; return p;
  };
  float* inv_src = (float*)carve((size_t)N*4);
  float* inv_dst = (float*)carve((size_t)N*4);
  int* row_ptr = (int*)carve((size_t)(N+1)*4);
  int* col     = (int*)carve((size_t)E*4);
  __bf16* Wsp = (__bf16*)carve(6*128*128*2);   // hi0,lo0,hi1,lo1,hi2,lo2
  float* hsA = (float*)carve((size_t)N*128*4);
  float* hsB = (float*)carve((size_t)N*128*4);

  // CSR-build temporaries alias hsB (dead until layer 1 writes it).
  unsigned* T = (unsigned*)hsB;
  unsigned* cntA   = T;
  unsigned* cntB   = cntA + (size_t)B1*NB;
  unsigned* totals = cntB + (size_t)B1*NB;
  unsigned* baseA  = totals + 2*(size_t)NB;
  unsigned* baseB  = baseA + (NB+1);
  unsigned* stagedA = baseB + (NB+1);
  unsigned char* stagedB = (unsigned char*)(stagedA + (size_t)B1*chunk);

  scatter_count_kernel<<<B1 + WPREP_BLOCKS, 256, 0, stream>>>(
      src, dst, cntA, cntB, stagedA, stagedB, W0, W1, W2, Wsp, E, NB);
  totals_kernel<<<dim3(ceil_div(NB,256), 2), 256, 0, stream>>>(cntA, cntB, totals, NB, E);
  scan_base_kernel<<<1, NBMAX, 0, stream>>>(totals, baseA, baseB, NB, E);
  csr_finalize_kernel<<<NB, 256, 0, stream>>>(stagedA, stagedB, cntA, cntB, baseA,
                                              row_ptr, inv_dst, inv_src, col, N, E, NB);

  const int fgrid = ceil_div(N, 64);
  __bf16 *Whi0 = Wsp,            *Wlo0 = Wsp + 16384;
  __bf16 *Whi1 = Wsp + 2*16384,  *Wlo1 = Wsp + 3*16384;
  __bf16 *Whi2 = Wsp + 4*16384,  *Wlo2 = Wsp + 5*16384;
  // layer 0: feats -> hsA (gather scales by inv_src; epilogue pre-scales next
  // layer's src mult via out_scale=inv_src)
  fused_agg_gemm_kernel<true><<<fgrid, 512, 0, stream>>>(
      row_ptr, col, feats, inv_src, inv_dst, Whi0, Wlo0, b0, inv_src, hsA, N);
  // layer 1: hsA -> hsB
  fused_agg_gemm_kernel<false><<<fgrid, 512, 0, stream>>>(
      row_ptr, col, hsA, nullptr, inv_dst, Whi1, Wlo1, b1, inv_src, hsB, N);
  // layer 2: hsB -> hsA (no out_scale)
  fused_agg_gemm_kernel<false><<<fgrid, 512, 0, stream>>>(
      row_ptr, col, hsB, nullptr, inv_dst, Whi2, Wlo2, b2, nullptr, hsA, N);
  // fused pool + MLP head
  head_kernel<<<ceil_div(G,8), 256, 0, stream>>>(hsA, gid, Wm0, bm0, Wm1, bm1, Wm2, bm2, out, N, G);
}